// Round 6
// baseline (11685.261 us; speedup 1.0000x reference)
//
#include <hip/hip_runtime.h>

// ---------------------------------------------------------------------------
// 2-layer LSTM (S=4096, B=64, I=14, H=256) + ReLU + FC(256->1), eval mode.
// WEIGHT-STATIONARY gate-sliced design: 32 active WGs (4 batch-groups x
// {2 layers x 4 gate-slices}), weights resident in VGPR/AGPR.
// R6: (a) SAME-XCD co-location: grid=64, active iff blockIdx%8<4; group
//     g = blockIdx%8, role = blockIdx>>3  ->  all 8 WGs of a group land on
//     one XCD (empirical round-robin XCD = bi%8). Exchange rings become
//     XCD-L2-local: publish-ack / notify / poll RTs ~200cyc not ~1400.
//     Correctness does NOT depend on the mapping (agent-scope atomics).
// (b) LDS bank-conflict fix: Ash row stride 300/524 halves (stride-words
//     22/6 mod 32 -> distinct banks across cols, 2-way max). Rows are 8-B
//     aligned only -> all row accesses are paired half4 (b64), no b128.
// Handshake (R5): producers publish tagged u64 words, s_waitcnt vmcnt(0),
// then post per-wave notify; consumers poll notifies only, single-shot
// speculative gather + tag-validate.
// ---------------------------------------------------------------------------

#define S_LEN 4096
#define BATCH 64
#define IN_DIM 14
#define HID 256
#define GATES 1024
#define K0 288        // layer0 K (h256 | x14 | pad18)
#define LDA0 300      // halves; 600B rows: 8-B aligned, 150w%32=22 -> 2-way max
#define K1 512        // layer1 K (h1 | hs0)
#define LDA1 524      // halves; 1048B rows: 8-B aligned, 262w%32=6 -> 2-way max
#define GST 260       // gate LDS row stride (f32): 2-way only (free)

#define NFY(L, g, j, wv) ((((((L)*4 + (g)) * 4 + (j)) * 8) + (wv)) * 16)

typedef _Float16 half8 __attribute__((ext_vector_type(8)));
typedef _Float16 half4 __attribute__((ext_vector_type(4)));
typedef float f32x4 __attribute__((ext_vector_type(4)));
typedef unsigned long long u64;
typedef unsigned int u32;

__device__ __forceinline__ float sigf(float z) { return 1.0f / (1.0f + __expf(-z)); }
__device__ __forceinline__ float tanhf2(float z) { return 2.0f / (1.0f + __expf(-2.0f * z)) - 1.0f; }

__device__ __forceinline__ u64 aload(const u64* p) {
    return __hip_atomic_load(p, __ATOMIC_RELAXED, __HIP_MEMORY_SCOPE_AGENT);
}
__device__ __forceinline__ void astore(u64* p, u64 v) {
    __hip_atomic_store(p, v, __ATOMIC_RELAXED, __HIP_MEMORY_SCOPE_AGENT);
}
__device__ __forceinline__ u32 aload32(const u32* p) {
    return __hip_atomic_load(p, __ATOMIC_RELAXED, __HIP_MEMORY_SCOPE_AGENT);
}
__device__ __forceinline__ void astore32(u32* p, u32 v) {
    __hip_atomic_store(p, v, __ATOMIC_RELAXED, __HIP_MEMORY_SCOPE_AGENT);
}
__device__ __forceinline__ u32 packh2(float a, float b) {
    union { _Float16 h[2]; u32 u; } q;
    q.h[0] = (_Float16)a; q.h[1] = (_Float16)b;
    return q.u;
}
// load MFMA A-fragment (8 halves) as two b64 reads (rows are 8-B aligned)
__device__ __forceinline__ half8 ldA(const _Float16* p) {
    half4 lo = *(const half4*)p;
    half4 hi = *(const half4*)(p + 4);
    return __builtin_shufflevector(lo, hi, 0, 1, 2, 3, 4, 5, 6, 7);
}
__device__ __forceinline__ void stA(_Float16* p, const float* src) {
    half4 lo, hi;
#pragma unroll
    for (int q2 = 0; q2 < 4; ++q2) { lo[q2] = (_Float16)src[q2]; hi[q2] = (_Float16)src[q2 + 4]; }
    *(half4*)p = lo;
    *(half4*)(p + 4) = hi;
}

// ---------------------------------------------------------------------------
__global__ void prep_weights(const float* __restrict__ Wih0, const float* __restrict__ Whh0,
                             const float* __restrict__ bih0, const float* __restrict__ bhh0,
                             const float* __restrict__ Wih1, const float* __restrict__ Whh1,
                             const float* __restrict__ bih1, const float* __restrict__ bhh1,
                             _Float16* __restrict__ wcat0, _Float16* __restrict__ wcat1,
                             float* __restrict__ b0, float* __restrict__ b1) {
    int idx0 = blockIdx.x * blockDim.x + threadIdx.x;
    int stride = gridDim.x * blockDim.x;
    for (int i = idx0; i < GATES * K0; i += stride) {
        int n = i / K0, k = i % K0;
        float v = 0.f;
        if (k < HID) v = Whh0[n * HID + k];
        else if (k < HID + IN_DIM) v = Wih0[n * IN_DIM + (k - HID)];
        wcat0[i] = (_Float16)v;
    }
    for (int i = idx0; i < GATES * K1; i += stride) {
        int n = i / K1, k = i % K1;
        float v = (k < HID) ? Whh1[n * HID + k] : Wih1[n * HID + (k - HID)];
        wcat1[i] = (_Float16)v;
    }
    for (int i = idx0; i < GATES; i += stride) {
        b0[i] = bih0[i] + bhh0[i];
        b1[i] = bih1[i] + bhh1[i];
    }
}

// ---------------------------------------------------------------------------
__global__ __launch_bounds__(512) void lstm_scan(
    const float* __restrict__ x, const float* __restrict__ h0g, const float* __restrict__ c0g,
    const _Float16* __restrict__ wcat0, const _Float16* __restrict__ wcat1,
    const float* __restrict__ b0, const float* __restrict__ b1,
    const float* __restrict__ wfc, const float* __restrict__ bfc,
    u64* __restrict__ h0ring, u64* __restrict__ h1ring,
    u32* __restrict__ nfy, u32* __restrict__ prog, float* __restrict__ out, int R0) {
    // SAME-XCD decode: XCD ~= blockIdx%8 (empirical round-robin). Group g's
    // 8 WGs all at bi%8==g -> one XCD. bi%8 in 4..7 idle.
    const int bi = blockIdx.x;
    const int g = bi & 7;
    if (g >= 4) return;
    const int role = bi >> 3;      // 0..7
    const int L = role >> 2;       // layer
    const int j = role & 3;        // gate slice (64 units)

    const int tid = threadIdx.x;
    const int w = tid >> 6;        // wave 0..7
    const int lane = tid & 63;
    const int quad = lane >> 4;
    const int col = lane & 15;
    const int c0b = g * 16;        // batch base
    const int pm = tid & 15;       // pointwise chain
    const int iu = tid >> 4;       // pointwise unit-pair index (0..31)
    const int pu = iu * 2;         // pointwise unit base (0..62, local)
    const int gm = tid >> 5;       // gather chain (word idx = tid)
    const int gu = tid & 31;       // gather unit-pair

    __shared__ __align__(16) _Float16 Ash[16 * LDA1];
    __shared__ float Gsh[16 * GST];
    __shared__ float WfS[HID];
    __shared__ u32 OwnH[512];

    u64* h0w = h0ring + (size_t)g * R0 * 2048;  // [slot][slice 4][512 words]
    u64* h1w = h1ring + (size_t)g * 4 * 2048;
    const int R0m = R0 - 1;

    int peer[3];
    { int c = 0; for (int p = 0; p < 4; ++p) if (p != j) peer[c++] = p; }

    if (L == 0) {
        // ================= layer 0 =================
        half8 wr[2][K0 / 32];
        float bs[2];
#pragma unroll
        for (int tt = 0; tt < 2; ++tt) {
            int t = w + 8 * tt;
            int n = (t >> 2) * 256 + j * 64 + (t & 3) * 16 + col;
            bs[tt] = b0[n];
            const _Float16* wp = wcat0 + (size_t)n * K0 + quad * 8;
#pragma unroll
            for (int kk = 0; kk < K0 / 32; ++kk) wr[tt][kk] = *(const half8*)(wp + kk * 32);
        }
        float cs0 = c0g[(size_t)(c0b + pm) * HID + j * 64 + pu];
        float cs1 = c0g[(size_t)(c0b + pm) * HID + j * 64 + pu + 1];
        {
            int m = tid >> 5, cw = tid & 31;
            const float* hp = h0g + (size_t)(c0b + m) * HID + cw * 8;
            float tmp[8];
#pragma unroll
            for (int q2 = 0; q2 < 8; ++q2) tmp[q2] = hp[q2];
            stA(&Ash[m * LDA0 + cw * 8], tmp);
            if (cw >= IN_DIM) Ash[m * LDA0 + HID + cw] = (_Float16)0.f;
        }
        const int xm = tid / IN_DIM, xd = tid - xm * IN_DIM;  // for tid<224
        if (tid < 16 * IN_DIM)
            Ash[xm * LDA0 + HID + xd] = (_Float16)x[(size_t)(c0b + xm) * IN_DIM + xd];
        __syncthreads();

        for (int s = 0; s < S_LEN; ++s) {
            // ---- phase1: spec issue + x prefetch + notify poll (wave0)
            float xpre = 0.f;
            if (tid < 16 * IN_DIM && s + 1 < S_LEN)
                xpre = x[((size_t)(s + 1) * BATCH + c0b + xm) * IN_DIM + xd];
            const u64* ap[3];
            u64 vv[3] = {0, 0, 0};
            if (s > 0) {
                const u64* base = h0w + (size_t)((s - 1) & R0m) * 2048;
#pragma unroll
                for (int i = 0; i < 3; ++i) { ap[i] = base + peer[i] * 512 + tid; vv[i] = aload(ap[i]); }
            }
            if (w == 0) {
                bool act = false; const u32* np = nullptr; int tgt = 0;
                if (lane < 24) {
                    act = (s > 0); np = nfy + NFY(0, g, peer[lane >> 3], lane & 7); tgt = s;
                } else if (lane < 28) {
                    act = ((s & 7) == 0) && (s + 2 > R0);
                    np = prog + g * 4 + (lane - 24); tgt = s + 2 - R0;
                }
                bool ok = !act;
                for (;;) {
                    if (!ok) ok = ((int)aload32(np) >= tgt);
                    if (__all(ok)) break;
                    __builtin_amdgcn_s_sleep(1);
                }
            }
            __syncthreads();
            // ---- phase2: validate + gather peers' h0[s-1]
            if (s > 0) {
#pragma unroll
                for (int i = 0; i < 3; ++i) {
                    while ((u32)(vv[i] >> 32) != (u32)s) vv[i] = aload(ap[i]);
                    *(u32*)&Ash[gm * LDA0 + peer[i] * 64 + 2 * gu] = (u32)vv[i];
                }
            }
            __syncthreads();
            // ---- phase3: MFMA + gates + pointwise + publish
            f32x4 acc0 = {bs[0], bs[0], bs[0], bs[0]};
            f32x4 acc1 = {bs[1], bs[1], bs[1], bs[1]};
#pragma unroll
            for (int kk = 0; kk < K0 / 32; ++kk) {
                half8 av = ldA(&Ash[col * LDA0 + kk * 32 + quad * 8]);
                acc0 = __builtin_amdgcn_mfma_f32_16x16x32_f16(av, wr[0][kk], acc0, 0, 0, 0);
                acc1 = __builtin_amdgcn_mfma_f32_16x16x32_f16(av, wr[1][kk], acc1, 0, 0, 0);
            }
#pragma unroll
            for (int r = 0; r < 4; ++r) {
                Gsh[(quad * 4 + r) * GST + w * 16 + col] = acc0[r];
                Gsh[(quad * 4 + r) * GST + (w + 8) * 16 + col] = acc1[r];
            }
            __syncthreads();
            {
                float iv = sigf(Gsh[pm * GST + pu]);
                float fv = sigf(Gsh[pm * GST + 64 + pu]);
                float gv = tanhf2(Gsh[pm * GST + 128 + pu]);
                float ov = sigf(Gsh[pm * GST + 192 + pu]);
                cs0 = fv * cs0 + iv * gv;
                float ha = ov * tanhf2(cs0);
                iv = sigf(Gsh[pm * GST + pu + 1]);
                fv = sigf(Gsh[pm * GST + 64 + pu + 1]);
                gv = tanhf2(Gsh[pm * GST + 128 + pu + 1]);
                ov = sigf(Gsh[pm * GST + 192 + pu + 1]);
                cs1 = fv * cs1 + iv * gv;
                float hb = ov * tanhf2(cs1);
                u32 hw = packh2(ha, hb);
                *(u32*)&Ash[pm * LDA0 + j * 64 + pu] = hw;
                astore(h0w + (size_t)(s & R0m) * 2048 + j * 512 + (pm * 32 + iu),
                       (u64)hw | ((u64)(u32)(s + 1) << 32));
            }
            asm volatile("s_waitcnt vmcnt(0)" ::: "memory");
            if (lane == 0) astore32(nfy + NFY(0, g, j, w), (u32)(s + 1));
            if (tid < 16 * IN_DIM && s + 1 < S_LEN)
                Ash[xm * LDA0 + HID + xd] = (_Float16)xpre;
            __syncthreads();
        }
    } else {
        // ================= layer 1 + fused FC =================
        half8 wr[2][K1 / 32];
        float bs[2];
#pragma unroll
        for (int tt = 0; tt < 2; ++tt) {
            int t = w + 8 * tt;
            int n = (t >> 2) * 256 + j * 64 + (t & 3) * 16 + col;
            bs[tt] = b1[n];
            const _Float16* wp = wcat1 + (size_t)n * K1 + quad * 8;
#pragma unroll
            for (int kk = 0; kk < K1 / 32; ++kk) wr[tt][kk] = *(const half8*)(wp + kk * 32);
        }
        for (int i = tid; i < HID; i += 512) WfS[i] = wfc[i];
        const float bfcv = bfc[0];
        float cs0 = c0g[(size_t)(BATCH + c0b + pm) * HID + j * 64 + pu];
        float cs1 = c0g[(size_t)(BATCH + c0b + pm) * HID + j * 64 + pu + 1];
        {
            int m = tid >> 5, cw = tid & 31;
            const float* hp = h0g + (size_t)(BATCH + c0b + m) * HID + cw * 8;
            float tmp[8];
#pragma unroll
            for (int q2 = 0; q2 < 8; ++q2) tmp[q2] = hp[q2];
            stA(&Ash[m * LDA1 + cw * 8], tmp);
        }
        u32* progself = prog + g * 4 + j;
        // pre-loop speculative issue of h0[0] words
        const u64* hp0[4];
        u64 hv0[4];
#pragma unroll
        for (int p = 0; p < 4; ++p) { hp0[p] = h0w + p * 512 + tid; hv0[p] = aload(hp0[p]); }
        __syncthreads();

        for (int s = 0; s <= S_LEN; ++s) {
            // ---- phase1: spec issue h1 peers + notify poll (wave0) + FC (wave7)
            const u64* ap[3];
            u64 vv[3] = {0, 0, 0};
            if (s > 0) {
                const u64* b1p = h1w + (size_t)((s - 1) & 3) * 2048;
#pragma unroll
                for (int i = 0; i < 3; ++i) { ap[i] = b1p + peer[i] * 512 + tid; vv[i] = aload(ap[i]); }
            }
            if (w == 0) {
                bool act = false; const u32* np = nullptr; int tgt = 0;
                if (lane < 24) {
                    act = (s > 0); np = nfy + NFY(1, g, peer[lane >> 3], lane & 7); tgt = s;
                } else if (lane < 56) {
                    int l2 = lane - 24;
                    act = (s < S_LEN); np = nfy + NFY(0, g, l2 >> 3, l2 & 7); tgt = s + 1;
                }
                bool ok = !act;
                for (;;) {
                    if (!ok) ok = ((int)aload32(np) >= tgt);
                    if (__all(ok)) break;
                    __builtin_amdgcn_s_sleep(1);
                }
            } else if (w == 7 && s >= 2) {
                // FC on h1[s-2] (coherent snapshot in Ash) -> out[s-2]
                int m = 4 * j + quad;
                float fa = 0.f;
#pragma unroll
                for (int k16 = 0; k16 < 16; ++k16) {
                    float hv = (float)Ash[m * LDA1 + col + 16 * k16];
                    fa += fmaxf(hv, 0.f) * WfS[col + 16 * k16];
                }
#pragma unroll
                for (int off = 1; off < 16; off <<= 1) fa += __shfl_xor(fa, off, 16);
                if (col == 0) out[(size_t)(s - 2) * BATCH + c0b + m] = fa + bfcv;
            }
            __syncthreads();
            // ---- phase2: validate + gather h1[s-1] (+own via OwnH) and h0[s]
            if (s > 0) {
#pragma unroll
                for (int i = 0; i < 3; ++i) {
                    while ((u32)(vv[i] >> 32) != (u32)s) vv[i] = aload(ap[i]);
                    *(u32*)&Ash[gm * LDA1 + peer[i] * 64 + 2 * gu] = (u32)vv[i];
                }
                *(u32*)&Ash[gm * LDA1 + j * 64 + 2 * gu] = OwnH[tid];
            }
            if (s < S_LEN) {
#pragma unroll
                for (int p = 0; p < 4; ++p) {
                    while ((u32)(hv0[p] >> 32) != (u32)(s + 1)) hv0[p] = aload(hp0[p]);
                    *(u32*)&Ash[gm * LDA1 + HID + p * 64 + 2 * gu] = (u32)hv0[p];
                }
            }
            __syncthreads();
            if (s == S_LEN) {
                if (w == 7) {  // final FC on h1[S_LEN-1]
                    int m = 4 * j + quad;
                    float fa = 0.f;
#pragma unroll
                    for (int k16 = 0; k16 < 16; ++k16) {
                        float hv = (float)Ash[m * LDA1 + col + 16 * k16];
                        fa += fmaxf(hv, 0.f) * WfS[col + 16 * k16];
                    }
#pragma unroll
                    for (int off = 1; off < 16; off <<= 1) fa += __shfl_xor(fa, off, 16);
                    if (col == 0) out[(size_t)(S_LEN - 1) * BATCH + c0b + m] = fa + bfcv;
                }
                break;
            }
            // ---- phase3: MFMA + gates + pointwise + publish + h0 prefetch
            f32x4 acc0 = {bs[0], bs[0], bs[0], bs[0]};
            f32x4 acc1 = {bs[1], bs[1], bs[1], bs[1]};
#pragma unroll
            for (int kk = 0; kk < K1 / 32; ++kk) {
                half8 av = ldA(&Ash[col * LDA1 + kk * 32 + quad * 8]);
                acc0 = __builtin_amdgcn_mfma_f32_16x16x32_f16(av, wr[0][kk], acc0, 0, 0, 0);
                acc1 = __builtin_amdgcn_mfma_f32_16x16x32_f16(av, wr[1][kk], acc1, 0, 0, 0);
            }
#pragma unroll
            for (int r = 0; r < 4; ++r) {
                Gsh[(quad * 4 + r) * GST + w * 16 + col] = acc0[r];
                Gsh[(quad * 4 + r) * GST + (w + 8) * 16 + col] = acc1[r];
            }
            __syncthreads();
            {
                float iv = sigf(Gsh[pm * GST + pu]);
                float fv = sigf(Gsh[pm * GST + 64 + pu]);
                float gv = tanhf2(Gsh[pm * GST + 128 + pu]);
                float ov = sigf(Gsh[pm * GST + 192 + pu]);
                cs0 = fv * cs0 + iv * gv;
                float ha = ov * tanhf2(cs0);
                iv = sigf(Gsh[pm * GST + pu + 1]);
                fv = sigf(Gsh[pm * GST + 64 + pu + 1]);
                gv = tanhf2(Gsh[pm * GST + 128 + pu + 1]);
                ov = sigf(Gsh[pm * GST + 192 + pu + 1]);
                cs1 = fv * cs1 + iv * gv;
                float hb = ov * tanhf2(cs1);
                u32 hw = packh2(ha, hb);
                OwnH[pm * 32 + iu] = hw;   // defer own-slice Ash update (FC snapshot)
                astore(h1w + (size_t)(s & 3) * 2048 + j * 512 + (pm * 32 + iu),
                       (u64)hw | ((u64)(u32)(s + 1) << 32));
            }
            asm volatile("s_waitcnt vmcnt(0)" ::: "memory");
            if (lane == 0) astore32(nfy + NFY(1, g, j, w), (u32)(s + 1));
            // prefetch h0[s+1] (L0 runs ahead; validated next step)
            if (s + 1 < S_LEN) {
#pragma unroll
                for (int p = 0; p < 4; ++p) {
                    hp0[p] = h0w + (size_t)((s + 1) & R0m) * 2048 + p * 512 + tid;
                    hv0[p] = aload(hp0[p]);
                }
            }
            if ((s & 7) == 7 && tid == 0) astore32(progself, (u32)(s + 1));
            __syncthreads();
        }
    }
}

// ---------------------------------------------------------------------------
extern "C" void kernel_launch(void* const* d_in, const int* in_sizes, int n_in,
                              void* d_out, int out_size, void* d_ws, size_t ws_size,
                              hipStream_t stream) {
    const float* x    = (const float*)d_in[0];
    const float* h0   = (const float*)d_in[1];
    const float* c0   = (const float*)d_in[2];
    const float* Wih0 = (const float*)d_in[3];
    const float* Whh0 = (const float*)d_in[4];
    const float* bih0 = (const float*)d_in[5];
    const float* bhh0 = (const float*)d_in[6];
    const float* Wih1 = (const float*)d_in[7];
    const float* Whh1 = (const float*)d_in[8];
    const float* bih1 = (const float*)d_in[9];
    const float* bhh1 = (const float*)d_in[10];
    const float* Wfc  = (const float*)d_in[11];
    const float* bfc  = (const float*)d_in[12];
    float* out = (float*)d_out;

    char* ws = (char*)d_ws;
    constexpr size_t OFF_WCAT0 = 0;
    constexpr size_t SZ_WCAT0 = (size_t)GATES * K0 * 2;   // 576 KB
    constexpr size_t OFF_WCAT1 = OFF_WCAT0 + SZ_WCAT0;
    constexpr size_t SZ_WCAT1 = (size_t)GATES * K1 * 2;   // 1 MB
    constexpr size_t OFF_B0 = OFF_WCAT1 + SZ_WCAT1;
    constexpr size_t OFF_B1 = OFF_B0 + 4096;
    constexpr size_t OFF_PROG = OFF_B1 + 4096;
    constexpr size_t SZ_PROG = 16384;
    constexpr size_t OFF_NFY = OFF_PROG + SZ_PROG;
    constexpr size_t SZ_NFY = 16384;                      // 256 words x 64B pad
    constexpr size_t OFF_H1R = OFF_NFY + SZ_NFY;
    constexpr size_t SZ_H1R = (size_t)4 * 4 * 2048 * 8;   // 256 KB
    constexpr size_t OFF_H0R = OFF_H1R + SZ_H1R;

    _Float16* wcat0 = (_Float16*)(ws + OFF_WCAT0);
    _Float16* wcat1 = (_Float16*)(ws + OFF_WCAT1);
    float* b0 = (float*)(ws + OFF_B0);
    float* b1 = (float*)(ws + OFF_B1);
    u32* prog = (u32*)(ws + OFF_PROG);
    u32* nfy = (u32*)(ws + OFF_NFY);
    u64* h1ring = (u64*)(ws + OFF_H1R);

    int R0 = 128;  // h0 ring slots; per group slot = 16 KB (tagged words)
    while (OFF_H0R + (size_t)4 * R0 * 2048 * 8 > ws_size && R0 > 16) R0 >>= 1;
    u64* h0ring = (u64*)(ws + OFF_H0R);

    hipMemsetAsync(prog, 0, SZ_PROG + SZ_NFY, stream);
    prep_weights<<<256, 256, 0, stream>>>(Wih0, Whh0, bih0, bhh0, Wih1, Whh1, bih1, bhh1,
                                          wcat0, wcat1, b0, b1);
    lstm_scan<<<64, 512, 0, stream>>>(x, h0, c0, wcat0, wcat1, b0, b1, Wfc, bfc,
                                      h0ring, h1ring, nfy, (u32*)prog, out, R0);
}